// Round 4
// baseline (61.013 us; speedup 1.0000x reference)
//
#include <hip/hip_runtime.h>
#include <math.h>

#define FEAT 64
#define NPW 4   // nodes per wave (fast path)

typedef float f32x4 __attribute__((ext_vector_type(4)));
typedef int   i32x4 __attribute__((ext_vector_type(4)));

// One 64-lane wave handles NPW=4 consecutive nodes.
// lane = (q = lane>>4 edge-quadrant, f4 = lane&15 float4-slot of feature row).
// Speculative score/col loads at assumed uniform-degree-16 offsets overlap the
// row_ptr verification; 16 independent row-gathers in flight per wave.
__global__ __launch_bounds__(256) void gat_agg_kernel(
    const void* __restrict__ row_ptr_v,
    const void* __restrict__ col_idx_v,
    const float* __restrict__ scores,
    const float* __restrict__ values,
    float* __restrict__ out,
    int num_nodes, long long num_edges)
{
    const int warp = threadIdx.x >> 6;
    const int lane = threadIdx.x & 63;
    const int wid0 = (blockIdx.x * 4 + warp) * NPW;
    if (wid0 >= num_nodes) return;

    const int* rp32 = (const int*)row_ptr_v;
    const bool idx64 = (rp32[1] == 0);   // int64 row_ptr => hi word of rp[0] is 0

    const int q  = lane >> 4;
    const int f4 = lane & 15;

    // ---- speculative loads at assumed offsets (bounds-clamped) ----
    long long base  = (long long)wid0 * 16;
    long long basec = base;
    if (basec > num_edges - (long long)(NPW * 16)) basec = num_edges - (long long)(NPW * 16);
    if (basec < 0) basec = 0;

    f32x4 sv[NPW];
    i32x4 cv[NPW];
    const bool can_spec = (num_edges >= (long long)(NPW * 16));
    if (can_spec) {
        const float* sb = scores + basec + (q << 2);
        const int*   cb = (const int*)col_idx_v + basec + (q << 2);
        #pragma unroll
        for (int n = 0; n < NPW; ++n) {
            sv[n] = __builtin_nontemporal_load((const f32x4*)(sb + n * 16));
            cv[n] = __builtin_nontemporal_load((const i32x4*)(cb + n * 16));
        }
    }

    // ---- verify uniform degree-16 layout (scalar loads, overlaps above) ----
    bool uni = true;
    #pragma unroll
    for (int n = 0; n <= NPW; ++n) {
        int node = wid0 + n;
        if (node <= num_nodes) uni &= (rp32[node] == node * 16);
    }
    const bool fast = (!idx64) && can_spec && uni && (basec == base) &&
                      (wid0 + NPW <= num_nodes);

    if (fast) {
        // ---- issue all 16 gathers first: max loads in flight ----
        f32x4 v[NPW][4];
        const float* vb = values + (f4 << 2);
        #pragma unroll
        for (int n = 0; n < NPW; ++n) {
            v[n][0] = *(const f32x4*)(vb + ((long long)cv[n].x << 6));
            v[n][1] = *(const f32x4*)(vb + ((long long)cv[n].y << 6));
            v[n][2] = *(const f32x4*)(vb + ((long long)cv[n].z << 6));
            v[n][3] = *(const f32x4*)(vb + ((long long)cv[n].w << 6));
        }

        // ---- softmax weights (VALU, overlaps gather latency) ----
        f32x4 w[NPW];
        float inv[NPW];
        #pragma unroll
        for (int n = 0; n < NPW; ++n) {
            float m = fmaxf(fmaxf(sv[n].x, sv[n].y), fmaxf(sv[n].z, sv[n].w));
            m = fmaxf(m, __shfl_xor(m, 16));
            m = fmaxf(m, __shfl_xor(m, 32));
            w[n].x = __expf(sv[n].x - m);
            w[n].y = __expf(sv[n].y - m);
            w[n].z = __expf(sv[n].z - m);
            w[n].w = __expf(sv[n].w - m);
            float s = w[n].x + w[n].y + w[n].z + w[n].w;
            s += __shfl_xor(s, 16);
            s += __shfl_xor(s, 32);
            inv[n] = 1.0f / s;
        }

        // ---- weighted accumulate + cross-quadrant reduce + store ----
        #pragma unroll
        for (int n = 0; n < NPW; ++n) {
            f32x4 acc;
            acc.x = w[n].x * v[n][0].x;              acc.y = w[n].x * v[n][0].y;
            acc.z = w[n].x * v[n][0].z;              acc.w = w[n].x * v[n][0].w;
            acc.x = fmaf(w[n].y, v[n][1].x, acc.x);  acc.y = fmaf(w[n].y, v[n][1].y, acc.y);
            acc.z = fmaf(w[n].y, v[n][1].z, acc.z);  acc.w = fmaf(w[n].y, v[n][1].w, acc.w);
            acc.x = fmaf(w[n].z, v[n][2].x, acc.x);  acc.y = fmaf(w[n].z, v[n][2].y, acc.y);
            acc.z = fmaf(w[n].z, v[n][2].z, acc.z);  acc.w = fmaf(w[n].z, v[n][2].w, acc.w);
            acc.x = fmaf(w[n].w, v[n][3].x, acc.x);  acc.y = fmaf(w[n].w, v[n][3].y, acc.y);
            acc.z = fmaf(w[n].w, v[n][3].z, acc.z);  acc.w = fmaf(w[n].w, v[n][3].w, acc.w);

            acc.x += __shfl_xor(acc.x, 16);  acc.x += __shfl_xor(acc.x, 32);
            acc.y += __shfl_xor(acc.y, 16);  acc.y += __shfl_xor(acc.y, 32);
            acc.z += __shfl_xor(acc.z, 16);  acc.z += __shfl_xor(acc.z, 32);
            acc.w += __shfl_xor(acc.w, 16);  acc.w += __shfl_xor(acc.w, 32);

            acc.x *= inv[n]; acc.y *= inv[n]; acc.z *= inv[n]; acc.w *= inv[n];

            if (q == 0) {
                f32x4* op = (f32x4*)(out + (long long)(wid0 + n) * FEAT + (f4 << 2));
                __builtin_nontemporal_store(acc, op);
            }
        }
    } else {
        // ---- generic fallback: lane = feature, any degree, either width ----
        for (int n = 0; n < NPW; ++n) {
            int node = wid0 + n;
            if (node >= num_nodes) break;
            long long start, end;
            if (idx64) {
                const long long* rp = (const long long*)row_ptr_v;
                start = rp[node]; end = rp[node + 1];
            } else {
                start = (long long)rp32[node]; end = (long long)rp32[node + 1];
            }
            float m = -INFINITY;
            for (long long e = start; e < end; ++e) m = fmaxf(m, scores[e]);
            float sum = 0.0f;
            for (long long e = start; e < end; ++e) sum += __expf(scores[e] - m);
            const float invs = (sum > 0.0f) ? 1.0f / sum : 0.0f;
            float acc = 0.0f;
            for (long long e = start; e < end; ++e) {
                long long c = idx64 ? ((const long long*)col_idx_v)[e]
                                    : (long long)((const int*)col_idx_v)[e];
                acc += __expf(scores[e] - m) * values[c * FEAT + lane];
            }
            out[(long long)node * FEAT + lane] = acc * invs;
        }
    }
}

extern "C" void kernel_launch(void* const* d_in, const int* in_sizes, int n_in,
                              void* d_out, int out_size, void* d_ws, size_t ws_size,
                              hipStream_t stream) {
    const void*  row_ptr = d_in[0];
    const void*  col_idx = d_in[1];
    const float* scores  = (const float*)d_in[2];
    const float* values  = (const float*)d_in[3];
    float*       out     = (float*)d_out;

    const int num_nodes = in_sizes[0] - 1;          // 100000
    const long long num_edges = (long long)in_sizes[2];
    const int nodes_per_block = 4 * NPW;            // 4 waves x NPW nodes
    const int blocks = (num_nodes + nodes_per_block - 1) / nodes_per_block;

    hipLaunchKernelGGL(gat_agg_kernel, dim3(blocks), dim3(256), 0, stream,
                       row_ptr, col_idx, scores, values, out, num_nodes, num_edges);
}

// Round 6
// 52.576 us; speedup vs baseline: 1.1605x; 1.1605x over previous
//
#include <hip/hip_runtime.h>
#include <math.h>

#define FEAT 64
#define NPW 4   // nodes per wave (fast path)

typedef float    f32x4 __attribute__((ext_vector_type(4)));
typedef int      i32x4 __attribute__((ext_vector_type(4)));
typedef _Float16 f16x4 __attribute__((ext_vector_type(4)));

// ---------- pre-pass: values fp32 -> fp16 (halves gather bytes) ----------
// NOTE: plain (cached-path) stores on values_h. A nontemporal store here
// bypasses the cache lines the harness's 0xAA poison populated, so the
// consumer kernel's loads see stale poison (R5 post-timing failure).
__global__ __launch_bounds__(256) void cvt_fp16_kernel(
    const float* __restrict__ values, _Float16* __restrict__ values_h, long long n4)
{
    long long i = (long long)blockIdx.x * blockDim.x + threadIdx.x;
    long long stride = (long long)gridDim.x * blockDim.x;
    for (; i < n4; i += stride) {
        f32x4 v = __builtin_nontemporal_load((const f32x4*)values + i);
        f16x4 h;
        h.x = (_Float16)v.x; h.y = (_Float16)v.y;
        h.z = (_Float16)v.z; h.w = (_Float16)v.w;
        ((f16x4*)values_h)[i] = h;   // regular store — stays coherent with poison lines
    }
}

// ---------- main: wave = NPW nodes, quadrant q owns 4 edges, f4 = float4-slot ----------
__global__ __launch_bounds__(256) void gat_agg_fp16_kernel(
    const void* __restrict__ row_ptr_v,
    const void* __restrict__ col_idx_v,
    const float* __restrict__ scores,
    const _Float16* __restrict__ values_h,
    const float* __restrict__ values,   // fp32 fallback path
    float* __restrict__ out,
    int num_nodes, long long num_edges)
{
    const int warp = threadIdx.x >> 6;
    const int lane = threadIdx.x & 63;
    const int wid0 = (blockIdx.x * 4 + warp) * NPW;
    if (wid0 >= num_nodes) return;

    const int* rp32 = (const int*)row_ptr_v;
    const bool idx64 = (rp32[1] == 0);   // int64 row_ptr => hi word of rp[0] is 0

    const int q  = lane >> 4;
    const int f4 = lane & 15;

    long long base  = (long long)wid0 * 16;
    long long basec = base;
    if (basec > num_edges - (long long)(NPW * 16)) basec = num_edges - (long long)(NPW * 16);
    if (basec < 0) basec = 0;

    f32x4 sv[NPW];
    i32x4 cv[NPW];
    const bool can_spec = (num_edges >= (long long)(NPW * 16));
    if (can_spec) {
        const float* sb = scores + basec + (q << 2);
        const int*   cb = (const int*)col_idx_v + basec + (q << 2);
        #pragma unroll
        for (int n = 0; n < NPW; ++n) {
            sv[n] = __builtin_nontemporal_load((const f32x4*)(sb + n * 16));
            cv[n] = __builtin_nontemporal_load((const i32x4*)(cb + n * 16));
        }
    }

    bool uni = true;
    #pragma unroll
    for (int n = 0; n <= NPW; ++n) {
        int node = wid0 + n;
        if (node <= num_nodes) uni &= (rp32[node] == node * 16);
    }
    const bool fast = (!idx64) && can_spec && uni && (basec == base) &&
                      (wid0 + NPW <= num_nodes);

    if (fast) {
        // issue all 16 half-row gathers (8B/lane, 128B/row) before any waits
        f16x4 v[NPW][4];
        const _Float16* vb = values_h + (f4 << 2);
        #pragma unroll
        for (int n = 0; n < NPW; ++n) {
            v[n][0] = *(const f16x4*)(vb + ((long long)cv[n].x << 6));
            v[n][1] = *(const f16x4*)(vb + ((long long)cv[n].y << 6));
            v[n][2] = *(const f16x4*)(vb + ((long long)cv[n].z << 6));
            v[n][3] = *(const f16x4*)(vb + ((long long)cv[n].w << 6));
        }

        f32x4 w[NPW];
        float inv[NPW];
        #pragma unroll
        for (int n = 0; n < NPW; ++n) {
            float m = fmaxf(fmaxf(sv[n].x, sv[n].y), fmaxf(sv[n].z, sv[n].w));
            m = fmaxf(m, __shfl_xor(m, 16));
            m = fmaxf(m, __shfl_xor(m, 32));
            w[n].x = __expf(sv[n].x - m);
            w[n].y = __expf(sv[n].y - m);
            w[n].z = __expf(sv[n].z - m);
            w[n].w = __expf(sv[n].w - m);
            float s = w[n].x + w[n].y + w[n].z + w[n].w;
            s += __shfl_xor(s, 16);
            s += __shfl_xor(s, 32);
            inv[n] = 1.0f / s;
        }

        #pragma unroll
        for (int n = 0; n < NPW; ++n) {
            f32x4 acc;
            acc.x = w[n].x * (float)v[n][0].x;              acc.y = w[n].x * (float)v[n][0].y;
            acc.z = w[n].x * (float)v[n][0].z;              acc.w = w[n].x * (float)v[n][0].w;
            acc.x = fmaf(w[n].y, (float)v[n][1].x, acc.x);  acc.y = fmaf(w[n].y, (float)v[n][1].y, acc.y);
            acc.z = fmaf(w[n].y, (float)v[n][1].z, acc.z);  acc.w = fmaf(w[n].y, (float)v[n][1].w, acc.w);
            acc.x = fmaf(w[n].z, (float)v[n][2].x, acc.x);  acc.y = fmaf(w[n].z, (float)v[n][2].y, acc.y);
            acc.z = fmaf(w[n].z, (float)v[n][2].z, acc.z);  acc.w = fmaf(w[n].z, (float)v[n][2].w, acc.w);
            acc.x = fmaf(w[n].w, (float)v[n][3].x, acc.x);  acc.y = fmaf(w[n].w, (float)v[n][3].y, acc.y);
            acc.z = fmaf(w[n].w, (float)v[n][3].z, acc.z);  acc.w = fmaf(w[n].w, (float)v[n][3].w, acc.w);

            acc.x += __shfl_xor(acc.x, 16);  acc.x += __shfl_xor(acc.x, 32);
            acc.y += __shfl_xor(acc.y, 16);  acc.y += __shfl_xor(acc.y, 32);
            acc.z += __shfl_xor(acc.z, 16);  acc.z += __shfl_xor(acc.z, 32);
            acc.w += __shfl_xor(acc.w, 16);  acc.w += __shfl_xor(acc.w, 32);

            acc.x *= inv[n]; acc.y *= inv[n]; acc.z *= inv[n]; acc.w *= inv[n];

            if (q == 0) {
                f32x4* op = (f32x4*)(out + (long long)(wid0 + n) * FEAT + (f4 << 2));
                __builtin_nontemporal_store(acc, op);  // consumer is host read — R4-proven safe
            }
        }
    } else {
        // generic fallback: lane = feature, any degree, either width, fp32 values
        for (int n = 0; n < NPW; ++n) {
            int node = wid0 + n;
            if (node >= num_nodes) break;
            long long start, end;
            if (idx64) {
                const long long* rp = (const long long*)row_ptr_v;
                start = rp[node]; end = rp[node + 1];
            } else {
                start = (long long)rp32[node]; end = (long long)rp32[node + 1];
            }
            float m = -INFINITY;
            for (long long e = start; e < end; ++e) m = fmaxf(m, scores[e]);
            float sum = 0.0f;
            for (long long e = start; e < end; ++e) sum += __expf(scores[e] - m);
            const float invs = (sum > 0.0f) ? 1.0f / sum : 0.0f;
            float acc = 0.0f;
            for (long long e = start; e < end; ++e) {
                long long c = idx64 ? ((const long long*)col_idx_v)[e]
                                    : (long long)((const int*)col_idx_v)[e];
                acc += __expf(scores[e] - m) * values[c * FEAT + lane];
            }
            out[(long long)node * FEAT + lane] = acc * invs;
        }
    }
}

// fp32-only variant (used when workspace is too small for the fp16 copy)
__global__ __launch_bounds__(256) void gat_agg_fp32_kernel(
    const void* __restrict__ row_ptr_v, const void* __restrict__ col_idx_v,
    const float* __restrict__ scores, const float* __restrict__ values,
    float* __restrict__ out, int num_nodes)
{
    const int wid  = blockIdx.x * 4 + (threadIdx.x >> 6);
    const int lane = threadIdx.x & 63;
    if (wid >= num_nodes) return;
    const int* rp32 = (const int*)row_ptr_v;
    const bool idx64 = (rp32[1] == 0);
    long long start, end;
    if (idx64) { const long long* rp = (const long long*)row_ptr_v; start = rp[wid]; end = rp[wid+1]; }
    else       { start = (long long)rp32[wid]; end = (long long)rp32[wid+1]; }
    float m = -INFINITY;
    for (long long e = start; e < end; ++e) m = fmaxf(m, scores[e]);
    float sum = 0.0f;
    for (long long e = start; e < end; ++e) sum += __expf(scores[e] - m);
    const float inv = (sum > 0.0f) ? 1.0f / sum : 0.0f;
    float acc = 0.0f;
    for (long long e = start; e < end; ++e) {
        long long c = idx64 ? ((const long long*)col_idx_v)[e]
                            : (long long)((const int*)col_idx_v)[e];
        acc += __expf(scores[e] - m) * values[c * FEAT + lane];
    }
    out[(long long)wid * FEAT + lane] = acc * inv;
}

extern "C" void kernel_launch(void* const* d_in, const int* in_sizes, int n_in,
                              void* d_out, int out_size, void* d_ws, size_t ws_size,
                              hipStream_t stream) {
    const void*  row_ptr = d_in[0];
    const void*  col_idx = d_in[1];
    const float* scores  = (const float*)d_in[2];
    const float* values  = (const float*)d_in[3];
    float*       out     = (float*)d_out;

    const int num_nodes = in_sizes[0] - 1;          // 100000
    const long long num_edges = (long long)in_sizes[2];
    const long long nvals = (long long)in_sizes[3]; // num_nodes * 64
    const size_t fp16_bytes = (size_t)nvals * sizeof(_Float16);

    if (ws_size >= fp16_bytes) {
        _Float16* values_h = (_Float16*)d_ws;
        const long long n4 = nvals / 4;
        int cvt_blocks = (int)((n4 + 255) / 256);
        if (cvt_blocks > 2048) cvt_blocks = 2048;
        hipLaunchKernelGGL(cvt_fp16_kernel, dim3(cvt_blocks), dim3(256), 0, stream,
                           values, values_h, n4);

        const int nodes_per_block = 4 * NPW;
        const int blocks = (num_nodes + nodes_per_block - 1) / nodes_per_block;
        hipLaunchKernelGGL(gat_agg_fp16_kernel, dim3(blocks), dim3(256), 0, stream,
                           row_ptr, col_idx, scores, values_h, values, out,
                           num_nodes, num_edges);
    } else {
        const int blocks = (num_nodes + 3) / 4;
        hipLaunchKernelGGL(gat_agg_fp32_kernel, dim3(blocks), dim3(256), 0, stream,
                           row_ptr, col_idx, scores, values, out, num_nodes);
    }
}